// Round 6
// baseline (437.433 us; speedup 1.0000x reference)
//
#include <hip/hip_runtime.h>
#include <hip/hip_bf16.h>
#include <cstdint>
#include <cstddef>

// Problem constants (fixed by the reference):
#define TTOK 4096
#define DM   1024
#define NE   8
#define KTOP 2
#define FFD  1024
#define CPER 1024       // TTOK*KTOP/NE tokens per expert (balanced)
#define MROWS 12288     // 8192 MoE permuted rows + 4096 shared rows

typedef __attribute__((ext_vector_type(8))) short frag8;   // 8 bf16 = 4 VGPRs
typedef __attribute__((ext_vector_type(4))) float f32x4;   // MFMA accumulator

static __device__ __forceinline__ unsigned short f2bf(float f) {
  unsigned int u = __float_as_uint(f);
  u += 0x7fff + ((u >> 16) & 1);     // round-to-nearest-even
  return (unsigned short)(u >> 16);
}
static __device__ __forceinline__ float bf2f(unsigned short u) {
  return __uint_as_float((unsigned int)u << 16);
}

static __device__ __forceinline__ void gld_lds16(const unsigned short* g, unsigned short* l) {
  __builtin_amdgcn_global_load_lds(
      (const __attribute__((address_space(1))) unsigned int*)g,
      (__attribute__((address_space(3))) unsigned int*)l,
      16, 0, 0);
}

// BK=32 tile: 128 rows x 4 segments of 16B. global_load_lds writes LINEAR LDS
// (wave base + lane*16B; per-lane LDS ptr ignored - m104/m108), so the bank
// swizzle is applied on the GLOBAL side: the lane filling linear slot seg
// fetches global segment cs=(seg&3)^((r>>1)&3). XOR involutive -> reader finds
// global (r,q) at lds_slot(r,q). Start banks over 8 rows:
// {0,16,4,20,8,24,12,28} -> 2-way alias only = free (m136; R3 measured
// SQ_LDS_BANK_CONFLICT == 0).
static __device__ __forceinline__ int lds_slot(int r, int cs) {
  return r * 4 + (cs ^ ((r >> 1) & 3));
}

static __device__ __forceinline__ void stage_tile(const unsigned short* __restrict__ src,
                                                  int row0, int k0,
                                                  unsigned short* lds, int tid) {
#pragma unroll
  for (int it = 0; it < 2; ++it) {
    int seg = it * 256 + tid;        // 512 linear 16B slots
    int r = seg >> 2;                // tile row
    int cs = (seg & 3) ^ ((r >> 1) & 3);   // swizzled global column segment
    gld_lds16(src + (size_t)(row0 + r) * 1024 + k0 + cs * 8, lds + seg * 8);
  }
}

// XCD-locality block swizzle for grid(8,96). HW dispatches round-robin:
// XCD = linear_id % 8. Map so each XCD owns 12 consecutive y-tiles (all x):
// A rows then live in exactly one XCD's L2 and each expert's weights are
// touched by <=2 XCDs. R5 measured FETCH 117->54.6 MB (~= ideal) with this.
static __device__ __forceinline__ void swizzle_xy(int& x, int& y) {
  int L = blockIdx.y * 8 + blockIdx.x;
  int xcd = L & 7;
  int s = L >> 3;                    // 0..95
  y = xcd * 12 + s % 12;
  x = s / 12;
}

// ---------------- permutation / routing ----------------
__global__ void perm_kernel(const int* __restrict__ idx, const float* __restrict__ tw,
                            int* __restrict__ cnt, int* __restrict__ rowdst,
                            int* __restrict__ inv, float* __restrict__ rowscale) {
  int i = blockIdx.x * 256 + threadIdx.x;        // i < TTOK*KTOP
  int e = idx[i];
  int pos = atomicAdd(&cnt[e], 1);               // order within expert irrelevant
  int j = e * CPER + pos;
  rowdst[j] = i >> 1;                            // token id (KTOP==2)
  rowscale[j] = tw[i];                           // fold topk weight into gemm2 epilogue
  inv[i] = j;                                    // inverse permutation for combine
}

// ---------------- pack activations: [12288][1024] bf16 ----------------
// rows 0..8191: permuted MoE copies; rows 8192..12287: the raw tokens (shared).
__global__ void pack_kernel(const float* __restrict__ x, const int* __restrict__ rowdst,
                            unsigned short* __restrict__ xall) {
  int j = blockIdx.x;
  int t = (j < 8192) ? rowdst[j] : (j - 8192);
  int c = threadIdx.x;                           // 256 threads * float4 = 1024 elems
  float4 v = ((const float4*)(x + (size_t)t * 1024))[c];
  ushort4 o;
  o.x = f2bf(v.x); o.y = f2bf(v.y); o.z = f2bf(v.z); o.w = f2bf(v.w);
  ((ushort4*)(xall + (size_t)j * 1024))[c] = o;
}

// ---------------- transpose + cast all 27 1024x1024 weight mats ----------------
// 64x64 tiles, float4 reads, ushort4 writes, LDS stride 65 (odd -> <=2-way).
// Outputs packed [9][1024][1024] per matrix kind; index 8 = shared expert.
__global__ void transw_kernel(const float* __restrict__ wg, const float* __restrict__ wu,
                              const float* __restrict__ wd, const float* __restrict__ sg,
                              const float* __restrict__ su, const float* __restrict__ sd,
                              unsigned short* __restrict__ owg, unsigned short* __restrict__ owu,
                              unsigned short* __restrict__ owd) {
  int z = blockIdx.z;
  const float* src; unsigned short* dst;
  if (z < 8)       { src = wg + (size_t)z * 1048576;        dst = owg + (size_t)z * 1048576; }
  else if (z < 16) { src = wu + (size_t)(z - 8) * 1048576;  dst = owu + (size_t)(z - 8) * 1048576; }
  else if (z < 24) { src = wd + (size_t)(z - 16) * 1048576; dst = owd + (size_t)(z - 16) * 1048576; }
  else if (z == 24){ src = sg; dst = owg + (size_t)8 * 1048576; }
  else if (z == 25){ src = su; dst = owu + (size_t)8 * 1048576; }
  else             { src = sd; dst = owd + (size_t)8 * 1048576; }
  __shared__ float tile[64][65];
  int bx = blockIdx.x * 64;   // src col base
  int by = blockIdx.y * 64;   // src row base
  int c4 = threadIdx.x & 15;  // float4 chunk within row
  int r0 = threadIdx.x >> 4;  // 0..15
#pragma unroll
  for (int i = 0; i < 4; ++i) {
    int r = r0 + 16 * i;
    float4 v = *(const float4*)&src[(size_t)(by + r) * 1024 + bx + c4 * 4];
    tile[r][c4 * 4 + 0] = v.x; tile[r][c4 * 4 + 1] = v.y;
    tile[r][c4 * 4 + 2] = v.z; tile[r][c4 * 4 + 3] = v.w;
  }
  __syncthreads();
#pragma unroll
  for (int i = 0; i < 4; ++i) {
    int f = r0 + 16 * i;       // dst row = src col bx+f
    ushort4 o;
    o.x = f2bf(tile[c4 * 4 + 0][f]);
    o.y = f2bf(tile[c4 * 4 + 1][f]);
    o.z = f2bf(tile[c4 * 4 + 2][f]);
    o.w = f2bf(tile[c4 * 4 + 3][f]);
    *(ushort4*)&dst[(size_t)(bx + f) * 1024 + by + c4 * 4] = o;
  }
}

// ---------------- shared-expert sigmoid gate -> rowscale[8192+t] ----------------
__global__ void gate_kernel(const float* __restrict__ x, const float* __restrict__ gw,
                            float* __restrict__ rowscale) {
  int t = blockIdx.x * 4 + (threadIdx.x >> 6);   // 4 waves = 4 tokens per block
  int lane = threadIdx.x & 63;
  const float4* xr = (const float4*)(x + (size_t)t * 1024);
  const float4* wr = (const float4*)gw;
  float s = 0.f;
#pragma unroll
  for (int c = lane; c < 256; c += 64) {
    float4 a = xr[c], b = wr[c];
    s += a.x * b.x + a.y * b.y + a.z * b.z + a.w * b.w;
  }
#pragma unroll
  for (int off = 32; off; off >>= 1) s += __shfl_down(s, off);
  if (lane == 0) rowscale[8192 + t] = 1.f / (1.f + __expf(-s));
}

// Expert id for a 128-row M-block: y<64 -> MoE expert y/8; else shared (8).
static __device__ __forceinline__ int eid_of(int y) { return (y < 64) ? (y >> 3) : 8; }

// ---------------- GEMM1: H = silu(A @ Wg) * (A @ Wu), bf16 out ----------------
// A: [12288][1024] bf16; Bg/Bu: [9][1024][1024] bf16, N-major (pre-transposed).
// grid (8, 96), block 256. BK=32. 3 blocks/CU: grid 768 = 3*256 exactly
// resident -> no tail round (R5's 2/CU left a half-occupancy tail, ~25% loss).
__global__ __launch_bounds__(256, 3) void gemm1_kernel(
    const unsigned short* __restrict__ A, const unsigned short* __restrict__ Bg,
    const unsigned short* __restrict__ Bu, unsigned short* __restrict__ H) {
  __shared__ __align__(16) unsigned short As[128 * 32];
  __shared__ __align__(16) unsigned short Bgs[128 * 32];
  __shared__ __align__(16) unsigned short Bus[128 * 32];
  int tid = threadIdx.x;
  int bx, by;
  swizzle_xy(bx, by);
  int e = eid_of(by);
  int row0 = by * 128;
  int col0 = bx * 128;
  const unsigned short* Bge = Bg + (size_t)e * 1048576;
  const unsigned short* Bue = Bu + (size_t)e * 1048576;

  int wave = tid >> 6, lane = tid & 63;
  int wm = wave >> 1, wn = wave & 1;             // 2x2 wave grid, 64x64 per wave
  int lr = lane & 15, q = lane >> 4;

  f32x4 accg[4][4], accu[4][4];
#pragma unroll
  for (int i = 0; i < 4; ++i)
#pragma unroll
    for (int j = 0; j < 4; ++j) {
      accg[i][j] = (f32x4){0.f, 0.f, 0.f, 0.f};
      accu[i][j] = (f32x4){0.f, 0.f, 0.f, 0.f};
    }

  for (int kt = 0; kt < 1024; kt += 32) {
    stage_tile(A, row0, kt, As, tid);
    stage_tile(Bge, col0, kt, Bgs, tid);
    stage_tile(Bue, col0, kt, Bus, tid);
    __syncthreads();                             // drains vmcnt for global_load_lds
    frag8 a[4], b0[4], b1[4];
#pragma unroll
    for (int i = 0; i < 4; ++i) {
      int r = wm * 64 + i * 16 + lr;
      a[i] = *(const frag8*)&As[lds_slot(r, q) * 8];
    }
#pragma unroll
    for (int j = 0; j < 4; ++j) {
      int r = wn * 64 + j * 16 + lr;
      b0[j] = *(const frag8*)&Bgs[lds_slot(r, q) * 8];
      b1[j] = *(const frag8*)&Bus[lds_slot(r, q) * 8];
    }
#pragma unroll
    for (int i = 0; i < 4; ++i)
#pragma unroll
      for (int j = 0; j < 4; ++j) {
        accg[i][j] = __builtin_amdgcn_mfma_f32_16x16x32_bf16(a[i], b0[j], accg[i][j], 0, 0, 0);
        accu[i][j] = __builtin_amdgcn_mfma_f32_16x16x32_bf16(a[i], b1[j], accu[i][j], 0, 0, 0);
      }
    __syncthreads();
  }
#pragma unroll
  for (int i = 0; i < 4; ++i)
#pragma unroll
    for (int j = 0; j < 4; ++j)
#pragma unroll
      for (int r = 0; r < 4; ++r) {
        int m = row0 + wm * 64 + i * 16 + q * 4 + r;   // C/D: row=quad*4+reg
        int n = col0 + wn * 64 + j * 16 + lr;          //       col=lane&15
        float gv = accg[i][j][r];
        float hv = gv / (1.f + __expf(-gv)) * accu[i][j][r];
        H[(size_t)m * 1024 + n] = f2bf(hv);
      }
}

// ---------------- GEMM2: Y = rowscale * (A @ Wd), bf16 out ----------------
__global__ __launch_bounds__(256, 3) void gemm2_kernel(
    const unsigned short* __restrict__ A, const unsigned short* __restrict__ B,
    const float* __restrict__ rowscale, unsigned short* __restrict__ Y) {
  __shared__ __align__(16) unsigned short As[128 * 32];
  __shared__ __align__(16) unsigned short Bs[128 * 32];
  int tid = threadIdx.x;
  int bx, by;
  swizzle_xy(bx, by);
  int e = eid_of(by);
  int row0 = by * 128;
  int col0 = bx * 128;
  const unsigned short* Be = B + (size_t)e * 1048576;

  int wave = tid >> 6, lane = tid & 63;
  int wm = wave >> 1, wn = wave & 1;
  int lr = lane & 15, q = lane >> 4;

  f32x4 acc[4][4];
#pragma unroll
  for (int i = 0; i < 4; ++i)
#pragma unroll
    for (int j = 0; j < 4; ++j) acc[i][j] = (f32x4){0.f, 0.f, 0.f, 0.f};

  for (int kt = 0; kt < 1024; kt += 32) {
    stage_tile(A, row0, kt, As, tid);
    stage_tile(Be, col0, kt, Bs, tid);
    __syncthreads();
    frag8 a[4], b[4];
#pragma unroll
    for (int i = 0; i < 4; ++i) {
      int r = wm * 64 + i * 16 + lr;
      a[i] = *(const frag8*)&As[lds_slot(r, q) * 8];
    }
#pragma unroll
    for (int j = 0; j < 4; ++j) {
      int r = wn * 64 + j * 16 + lr;
      b[j] = *(const frag8*)&Bs[lds_slot(r, q) * 8];
    }
#pragma unroll
    for (int i = 0; i < 4; ++i)
#pragma unroll
      for (int j = 0; j < 4; ++j)
        acc[i][j] = __builtin_amdgcn_mfma_f32_16x16x32_bf16(a[i], b[j], acc[i][j], 0, 0, 0);
    __syncthreads();
  }
#pragma unroll
  for (int i = 0; i < 4; ++i)
#pragma unroll
    for (int r = 0; r < 4; ++r) {
      int m = row0 + wm * 64 + i * 16 + q * 4 + r;
      float sc = rowscale[m];
#pragma unroll
      for (int j = 0; j < 4; ++j) {
        int n = col0 + wn * 64 + j * 16 + lr;
        Y[(size_t)m * 1024 + n] = f2bf(sc * acc[i][j][r]);
      }
    }
}

// ---------------- final combine: out[t] = Y[j0] + Y[j1] + Y[8192+t] ----------
__global__ void combine_kernel(const unsigned short* __restrict__ Y,
                               const int* __restrict__ inv, float* __restrict__ out) {
  int t = blockIdx.x;
  int c = threadIdx.x;                           // 256 threads * 4 elems
  int j0 = inv[2 * t], j1 = inv[2 * t + 1];
  ushort4 a = ((const ushort4*)(Y + (size_t)j0 * 1024))[c];
  ushort4 b = ((const ushort4*)(Y + (size_t)j1 * 1024))[c];
  ushort4 s = ((const ushort4*)(Y + (size_t)(8192 + t) * 1024))[c];
  float4 o;
  o.x = bf2f(a.x) + bf2f(b.x) + bf2f(s.x);
  o.y = bf2f(a.y) + bf2f(b.y) + bf2f(s.y);
  o.z = bf2f(a.z) + bf2f(b.z) + bf2f(s.z);
  o.w = bf2f(a.w) + bf2f(b.w) + bf2f(s.w);
  ((float4*)(out + (size_t)t * 1024))[c] = o;
}

extern "C" void kernel_launch(void* const* d_in, const int* in_sizes, int n_in,
                              void* d_out, int out_size, void* d_ws, size_t ws_size,
                              hipStream_t stream) {
  (void)in_sizes; (void)n_in; (void)out_size; (void)ws_size;
  const float* hidden  = (const float*)d_in[0];
  const float* topk_w  = (const float*)d_in[1];
  const float* w_gate  = (const float*)d_in[2];
  const float* w_up    = (const float*)d_in[3];
  const float* w_down  = (const float*)d_in[4];
  const float* sw_gate = (const float*)d_in[5];
  const float* sw_up   = (const float*)d_in[6];
  const float* sw_down = (const float*)d_in[7];
  const float* sgw     = (const float*)d_in[8];
  const int*   topk_i  = (const int*)d_in[9];
  float* out = (float*)d_out;

  char* p = (char*)d_ws;
  auto alloc = [&](size_t bytes) {
    char* r = p;
    p += (bytes + 255) & ~(size_t)255;
    return r;
  };
  unsigned short* Wg_all = (unsigned short*)alloc((size_t)9 * 1048576 * 2);  // [9][1024][1024]
  unsigned short* Wu_all = (unsigned short*)alloc((size_t)9 * 1048576 * 2);
  unsigned short* Wd_all = (unsigned short*)alloc((size_t)9 * 1048576 * 2);
  unsigned short* Xall   = (unsigned short*)alloc((size_t)MROWS * 1024 * 2); // also reused as Y
  unsigned short* Hall   = (unsigned short*)alloc((size_t)MROWS * 1024 * 2);
  int*   cnt      = (int*)alloc(NE * 4);
  int*   rowdst   = (int*)alloc((size_t)TTOK * KTOP * 4);
  int*   inv      = (int*)alloc((size_t)TTOK * KTOP * 4);
  float* rowscale = (float*)alloc((size_t)MROWS * 4);
  unsigned short* Yall = Xall;   // Xall is dead after gemm1; alias to save ws

  hipMemsetAsync(cnt, 0, NE * 4, stream);

  perm_kernel<<<TTOK * KTOP / 256, 256, 0, stream>>>(topk_i, topk_w, cnt, rowdst, inv, rowscale);
  pack_kernel<<<MROWS, 256, 0, stream>>>(hidden, rowdst, Xall);
  transw_kernel<<<dim3(16, 16, 27), 256, 0, stream>>>(
      w_gate, w_up, w_down, sw_gate, sw_up, sw_down, Wg_all, Wu_all, Wd_all);
  gate_kernel<<<TTOK / 4, 256, 0, stream>>>(hidden, sgw, rowscale);

  gemm1_kernel<<<dim3(8, 96), 256, 0, stream>>>(Xall, Wg_all, Wu_all, Hall);
  gemm2_kernel<<<dim3(8, 96), 256, 0, stream>>>(Hall, Wd_all, rowscale, Yall);
  combine_kernel<<<TTOK, 256, 0, stream>>>(Yall, inv, out);
}

// Round 7
// 370.788 us; speedup vs baseline: 1.1797x; 1.1797x over previous
//
#include <hip/hip_runtime.h>
#include <hip/hip_bf16.h>
#include <cstdint>
#include <cstddef>

// Problem constants (fixed by the reference):
#define TTOK 4096
#define DM   1024
#define NE   8
#define KTOP 2
#define FFD  1024
#define CPER 1024       // TTOK*KTOP/NE tokens per expert (balanced)
#define MROWS 12288     // 8192 MoE permuted rows + 4096 shared rows

typedef __attribute__((ext_vector_type(8))) short frag8;   // 8 bf16 = 4 VGPRs
typedef __attribute__((ext_vector_type(4))) float f32x4;   // MFMA accumulator

static __device__ __forceinline__ unsigned short f2bf(float f) {
  unsigned int u = __float_as_uint(f);
  u += 0x7fff + ((u >> 16) & 1);     // round-to-nearest-even
  return (unsigned short)(u >> 16);
}
static __device__ __forceinline__ float bf2f(unsigned short u) {
  return __uint_as_float((unsigned int)u << 16);
}

static __device__ __forceinline__ void gld_lds16(const unsigned short* g, unsigned short* l) {
  __builtin_amdgcn_global_load_lds(
      (const __attribute__((address_space(1))) unsigned int*)g,
      (__attribute__((address_space(3))) unsigned int*)l,
      16, 0, 0);
}

// BK=32 tile: 128 rows x 4 segments of 16B. global_load_lds writes LINEAR LDS
// (wave base + lane*16B; per-lane LDS ptr ignored - m104/m108), so the bank
// swizzle is applied on the GLOBAL side: lane filling linear slot seg fetches
// global segment cs=(seg&3)^((r>>1)&3); XOR involutive -> reader finds global
// (r,q) at lds_slot(r,q). R3/R5 measured SQ_LDS_BANK_CONFLICT == 0.
static __device__ __forceinline__ int lds_slot(int r, int cs) {
  return r * 4 + (cs ^ ((r >> 1) & 3));
}

static __device__ __forceinline__ void stage_tile(const unsigned short* __restrict__ src,
                                                  int row0, int k0,
                                                  unsigned short* lds, int tid) {
#pragma unroll
  for (int it = 0; it < 2; ++it) {
    int seg = it * 256 + tid;        // 512 linear 16B slots
    int r = seg >> 2;                // tile row
    int cs = (seg & 3) ^ ((r >> 1) & 3);   // swizzled global column segment
    gld_lds16(src + (size_t)(row0 + r) * 1024 + k0 + cs * 8, lds + seg * 8);
  }
}

// XCD-locality block swizzle for grid(8,96): XCD = linear_id % 8; each XCD
// owns 12 consecutive y-tiles (all x). R5 measured FETCH 117->54.6 MB.
static __device__ __forceinline__ void swizzle_xy(int& x, int& y) {
  int L = blockIdx.y * 8 + blockIdx.x;
  int xcd = L & 7;
  int s = L >> 3;                    // 0..95
  y = xcd * 12 + s % 12;
  x = s / 12;
}

// ---------------- fused routing + pack + gate ----------------
// grid 12288 blocks x 256 threads.
// Blocks 0..8191 (MoE rows): lane0 routes flat pair i -> permuted row j
// (atomicAdd within expert; order irrelevant), records inv/rowscale; block
// copies token row (fp32 -> bf16) into Xall[j].
// Blocks 8192..12287 (shared rows): copy token row into Xall[i] AND compute
// the sigmoid gate dot(hidden[t], gw) -> rowscale[i] while the data is live.
__global__ void route_pack_kernel(const float* __restrict__ x, const int* __restrict__ idx,
                                  const float* __restrict__ tw, const float* __restrict__ gw,
                                  int* __restrict__ cnt, int* __restrict__ inv,
                                  float* __restrict__ rowscale,
                                  unsigned short* __restrict__ xall) {
  int i = blockIdx.x;
  int tid = threadIdx.x;
  if (i < 8192) {
    __shared__ int sj;
    if (tid == 0) {
      int e = idx[i];
      int pos = atomicAdd(&cnt[e], 1);
      int j = e * CPER + pos;
      inv[i] = j;
      rowscale[j] = tw[i];
      sj = j;
    }
    __syncthreads();
    int j = sj;
    int t = i >> 1;                                // token id (KTOP==2)
    float4 v = ((const float4*)(x + (size_t)t * 1024))[tid];
    ushort4 o;
    o.x = f2bf(v.x); o.y = f2bf(v.y); o.z = f2bf(v.z); o.w = f2bf(v.w);
    ((ushort4*)(xall + (size_t)j * 1024))[tid] = o;
  } else {
    int t = i - 8192;
    float4 v = ((const float4*)(x + (size_t)t * 1024))[tid];
    ushort4 o;
    o.x = f2bf(v.x); o.y = f2bf(v.y); o.z = f2bf(v.z); o.w = f2bf(v.w);
    ((ushort4*)(xall + (size_t)i * 1024))[tid] = o;
    // gate dot while v is in registers
    float4 g = ((const float4*)gw)[tid];
    float s = v.x * g.x + v.y * g.y + v.z * g.z + v.w * g.w;
#pragma unroll
    for (int off = 32; off; off >>= 1) s += __shfl_down(s, off);
    __shared__ float ws[4];
    if ((tid & 63) == 0) ws[tid >> 6] = s;
    __syncthreads();
    if (tid == 0) {
      float tot = ws[0] + ws[1] + ws[2] + ws[3];
      rowscale[i] = 1.f / (1.f + __expf(-tot));
    }
  }
}

// ---------------- transpose + cast all 27 1024x1024 weight mats ----------------
// 64x64 tiles, float4 reads, ushort4 writes, LDS stride 65 (odd -> <=2-way).
// Outputs packed [9][1024][1024] per matrix kind; index 8 = shared expert.
__global__ void transw_kernel(const float* __restrict__ wg, const float* __restrict__ wu,
                              const float* __restrict__ wd, const float* __restrict__ sg,
                              const float* __restrict__ su, const float* __restrict__ sd,
                              unsigned short* __restrict__ owg, unsigned short* __restrict__ owu,
                              unsigned short* __restrict__ owd) {
  int z = blockIdx.z;
  const float* src; unsigned short* dst;
  if (z < 8)       { src = wg + (size_t)z * 1048576;        dst = owg + (size_t)z * 1048576; }
  else if (z < 16) { src = wu + (size_t)(z - 8) * 1048576;  dst = owu + (size_t)(z - 8) * 1048576; }
  else if (z < 24) { src = wd + (size_t)(z - 16) * 1048576; dst = owd + (size_t)(z - 16) * 1048576; }
  else if (z == 24){ src = sg; dst = owg + (size_t)8 * 1048576; }
  else if (z == 25){ src = su; dst = owu + (size_t)8 * 1048576; }
  else             { src = sd; dst = owd + (size_t)8 * 1048576; }
  __shared__ float tile[64][65];
  int bx = blockIdx.x * 64;   // src col base
  int by = blockIdx.y * 64;   // src row base
  int c4 = threadIdx.x & 15;  // float4 chunk within row
  int r0 = threadIdx.x >> 4;  // 0..15
#pragma unroll
  for (int i = 0; i < 4; ++i) {
    int r = r0 + 16 * i;
    float4 v = *(const float4*)&src[(size_t)(by + r) * 1024 + bx + c4 * 4];
    tile[r][c4 * 4 + 0] = v.x; tile[r][c4 * 4 + 1] = v.y;
    tile[r][c4 * 4 + 2] = v.z; tile[r][c4 * 4 + 3] = v.w;
  }
  __syncthreads();
#pragma unroll
  for (int i = 0; i < 4; ++i) {
    int f = r0 + 16 * i;       // dst row = src col bx+f
    ushort4 o;
    o.x = f2bf(tile[c4 * 4 + 0][f]);
    o.y = f2bf(tile[c4 * 4 + 1][f]);
    o.z = f2bf(tile[c4 * 4 + 2][f]);
    o.w = f2bf(tile[c4 * 4 + 3][f]);
    *(ushort4*)&dst[(size_t)(bx + f) * 1024 + by + c4 * 4] = o;
  }
}

// Expert id for a 128-row M-block: y<64 -> MoE expert y/8; else shared (8).
static __device__ __forceinline__ int eid_of(int y) { return (y < 64) ? (y >> 3) : 8; }

// ---------------- GEMM1: H = silu(A @ Wg) * (A @ Wu), bf16 out ----------------
// R5-proven config: BK=32, 2 blocks/CU. Do NOT raise launch_bounds: the kernel
// needs 128 acc regs + ~100 VGPRs; (256,3) spilled accumulators to scratch
// (R6: WRITE 24.6->469 MB, gemm1 75->185 us).
__global__ __launch_bounds__(256, 2) void gemm1_kernel(
    const unsigned short* __restrict__ A, const unsigned short* __restrict__ Bg,
    const unsigned short* __restrict__ Bu, unsigned short* __restrict__ H) {
  __shared__ __align__(16) unsigned short As[128 * 32];
  __shared__ __align__(16) unsigned short Bgs[128 * 32];
  __shared__ __align__(16) unsigned short Bus[128 * 32];
  int tid = threadIdx.x;
  int bx, by;
  swizzle_xy(bx, by);
  int e = eid_of(by);
  int row0 = by * 128;
  int col0 = bx * 128;
  const unsigned short* Bge = Bg + (size_t)e * 1048576;
  const unsigned short* Bue = Bu + (size_t)e * 1048576;

  int wave = tid >> 6, lane = tid & 63;
  int wm = wave >> 1, wn = wave & 1;             // 2x2 wave grid, 64x64 per wave
  int lr = lane & 15, q = lane >> 4;

  f32x4 accg[4][4], accu[4][4];
#pragma unroll
  for (int i = 0; i < 4; ++i)
#pragma unroll
    for (int j = 0; j < 4; ++j) {
      accg[i][j] = (f32x4){0.f, 0.f, 0.f, 0.f};
      accu[i][j] = (f32x4){0.f, 0.f, 0.f, 0.f};
    }

  for (int kt = 0; kt < 1024; kt += 32) {
    stage_tile(A, row0, kt, As, tid);
    stage_tile(Bge, col0, kt, Bgs, tid);
    stage_tile(Bue, col0, kt, Bus, tid);
    __syncthreads();                             // drains vmcnt for global_load_lds
    frag8 a[4], b0[4], b1[4];
#pragma unroll
    for (int i = 0; i < 4; ++i) {
      int r = wm * 64 + i * 16 + lr;
      a[i] = *(const frag8*)&As[lds_slot(r, q) * 8];
    }
#pragma unroll
    for (int j = 0; j < 4; ++j) {
      int r = wn * 64 + j * 16 + lr;
      b0[j] = *(const frag8*)&Bgs[lds_slot(r, q) * 8];
      b1[j] = *(const frag8*)&Bus[lds_slot(r, q) * 8];
    }
#pragma unroll
    for (int i = 0; i < 4; ++i)
#pragma unroll
      for (int j = 0; j < 4; ++j) {
        accg[i][j] = __builtin_amdgcn_mfma_f32_16x16x32_bf16(a[i], b0[j], accg[i][j], 0, 0, 0);
        accu[i][j] = __builtin_amdgcn_mfma_f32_16x16x32_bf16(a[i], b1[j], accu[i][j], 0, 0, 0);
      }
    __syncthreads();
  }
#pragma unroll
  for (int i = 0; i < 4; ++i)
#pragma unroll
    for (int j = 0; j < 4; ++j)
#pragma unroll
      for (int r = 0; r < 4; ++r) {
        int m = row0 + wm * 64 + i * 16 + q * 4 + r;   // C/D: row=quad*4+reg
        int n = col0 + wn * 64 + j * 16 + lr;          //       col=lane&15
        float gv = accg[i][j][r];
        float hv = gv / (1.f + __expf(-gv)) * accu[i][j][r];
        H[(size_t)m * 1024 + n] = f2bf(hv);
      }
}

// ---------------- GEMM2: Y = rowscale * (A @ Wd), bf16 out ----------------
__global__ __launch_bounds__(256, 2) void gemm2_kernel(
    const unsigned short* __restrict__ A, const unsigned short* __restrict__ B,
    const float* __restrict__ rowscale, unsigned short* __restrict__ Y) {
  __shared__ __align__(16) unsigned short As[128 * 32];
  __shared__ __align__(16) unsigned short Bs[128 * 32];
  int tid = threadIdx.x;
  int bx, by;
  swizzle_xy(bx, by);
  int e = eid_of(by);
  int row0 = by * 128;
  int col0 = bx * 128;
  const unsigned short* Be = B + (size_t)e * 1048576;

  int wave = tid >> 6, lane = tid & 63;
  int wm = wave >> 1, wn = wave & 1;
  int lr = lane & 15, q = lane >> 4;

  f32x4 acc[4][4];
#pragma unroll
  for (int i = 0; i < 4; ++i)
#pragma unroll
    for (int j = 0; j < 4; ++j) acc[i][j] = (f32x4){0.f, 0.f, 0.f, 0.f};

  for (int kt = 0; kt < 1024; kt += 32) {
    stage_tile(A, row0, kt, As, tid);
    stage_tile(Be, col0, kt, Bs, tid);
    __syncthreads();
    frag8 a[4], b[4];
#pragma unroll
    for (int i = 0; i < 4; ++i) {
      int r = wm * 64 + i * 16 + lr;
      a[i] = *(const frag8*)&As[lds_slot(r, q) * 8];
    }
#pragma unroll
    for (int j = 0; j < 4; ++j) {
      int r = wn * 64 + j * 16 + lr;
      b[j] = *(const frag8*)&Bs[lds_slot(r, q) * 8];
    }
#pragma unroll
    for (int i = 0; i < 4; ++i)
#pragma unroll
      for (int j = 0; j < 4; ++j)
        acc[i][j] = __builtin_amdgcn_mfma_f32_16x16x32_bf16(a[i], b[j], acc[i][j], 0, 0, 0);
    __syncthreads();
  }
#pragma unroll
  for (int i = 0; i < 4; ++i)
#pragma unroll
    for (int r = 0; r < 4; ++r) {
      int m = row0 + wm * 64 + i * 16 + q * 4 + r;
      float sc = rowscale[m];
#pragma unroll
      for (int j = 0; j < 4; ++j) {
        int n = col0 + wn * 64 + j * 16 + lr;
        Y[(size_t)m * 1024 + n] = f2bf(sc * acc[i][j][r]);
      }
    }
}

// ---------------- final combine: out[t] = Y[j0] + Y[j1] + Y[8192+t] ----------
__global__ void combine_kernel(const unsigned short* __restrict__ Y,
                               const int* __restrict__ inv, float* __restrict__ out) {
  int t = blockIdx.x;
  int c = threadIdx.x;                           // 256 threads * 4 elems
  int j0 = inv[2 * t], j1 = inv[2 * t + 1];
  ushort4 a = ((const ushort4*)(Y + (size_t)j0 * 1024))[c];
  ushort4 b = ((const ushort4*)(Y + (size_t)j1 * 1024))[c];
  ushort4 s = ((const ushort4*)(Y + (size_t)(8192 + t) * 1024))[c];
  float4 o;
  o.x = bf2f(a.x) + bf2f(b.x) + bf2f(s.x);
  o.y = bf2f(a.y) + bf2f(b.y) + bf2f(s.y);
  o.z = bf2f(a.z) + bf2f(b.z) + bf2f(s.z);
  o.w = bf2f(a.w) + bf2f(b.w) + bf2f(s.w);
  ((float4*)(out + (size_t)t * 1024))[c] = o;
}

extern "C" void kernel_launch(void* const* d_in, const int* in_sizes, int n_in,
                              void* d_out, int out_size, void* d_ws, size_t ws_size,
                              hipStream_t stream) {
  (void)in_sizes; (void)n_in; (void)out_size; (void)ws_size;
  const float* hidden  = (const float*)d_in[0];
  const float* topk_w  = (const float*)d_in[1];
  const float* w_gate  = (const float*)d_in[2];
  const float* w_up    = (const float*)d_in[3];
  const float* w_down  = (const float*)d_in[4];
  const float* sw_gate = (const float*)d_in[5];
  const float* sw_up   = (const float*)d_in[6];
  const float* sw_down = (const float*)d_in[7];
  const float* sgw     = (const float*)d_in[8];
  const int*   topk_i  = (const int*)d_in[9];
  float* out = (float*)d_out;

  char* p = (char*)d_ws;
  auto alloc = [&](size_t bytes) {
    char* r = p;
    p += (bytes + 255) & ~(size_t)255;
    return r;
  };
  unsigned short* Wg_all = (unsigned short*)alloc((size_t)9 * 1048576 * 2);  // [9][1024][1024]
  unsigned short* Wu_all = (unsigned short*)alloc((size_t)9 * 1048576 * 2);
  unsigned short* Wd_all = (unsigned short*)alloc((size_t)9 * 1048576 * 2);
  unsigned short* Xall   = (unsigned short*)alloc((size_t)MROWS * 1024 * 2); // also reused as Y
  unsigned short* Hall   = (unsigned short*)alloc((size_t)MROWS * 1024 * 2);
  int*   cnt      = (int*)alloc(NE * 4);
  int*   inv      = (int*)alloc((size_t)TTOK * KTOP * 4);
  float* rowscale = (float*)alloc((size_t)MROWS * 4);
  unsigned short* Yall = Xall;   // Xall is dead after gemm1; alias to save ws

  hipMemsetAsync(cnt, 0, NE * 4, stream);

  route_pack_kernel<<<MROWS, 256, 0, stream>>>(hidden, topk_i, topk_w, sgw,
                                               cnt, inv, rowscale, Xall);
  transw_kernel<<<dim3(16, 16, 27), 256, 0, stream>>>(
      w_gate, w_up, w_down, sw_gate, sw_up, sw_down, Wg_all, Wu_all, Wd_all);

  gemm1_kernel<<<dim3(8, 96), 256, 0, stream>>>(Xall, Wg_all, Wu_all, Hall);
  gemm2_kernel<<<dim3(8, 96), 256, 0, stream>>>(Hall, Wd_all, rowscale, Yall);
  combine_kernel<<<TTOK, 256, 0, stream>>>(Yall, inv, out);
}

// Round 8
// 318.910 us; speedup vs baseline: 1.3716x; 1.1627x over previous
//
#include <hip/hip_runtime.h>
#include <hip/hip_bf16.h>
#include <cstdint>
#include <cstddef>

// Problem constants (fixed by the reference):
#define TTOK 4096
#define DM   1024
#define NE   8
#define KTOP 2
#define FFD  1024
#define CPER 1024       // TTOK*KTOP/NE tokens per expert (balanced)
#define MROWS 12288     // 8192 MoE permuted rows + 4096 shared rows

typedef __attribute__((ext_vector_type(8))) short frag8;   // 8 bf16 = 4 VGPRs
typedef __attribute__((ext_vector_type(4))) float f32x4;   // MFMA accumulator

static __device__ __forceinline__ unsigned short f2bf(float f) {
  unsigned int u = __float_as_uint(f);
  u += 0x7fff + ((u >> 16) & 1);     // round-to-nearest-even
  return (unsigned short)(u >> 16);
}
static __device__ __forceinline__ float bf2f(unsigned short u) {
  return __uint_as_float((unsigned int)u << 16);
}

static __device__ __forceinline__ void gld_lds16(const unsigned short* g, unsigned short* l) {
  __builtin_amdgcn_global_load_lds(
      (const __attribute__((address_space(1))) unsigned int*)g,
      (__attribute__((address_space(3))) unsigned int*)l,
      16, 0, 0);
}

// BK=32 tile: 128 rows x 4 segments of 16B. global_load_lds writes LINEAR LDS
// (wave base + lane*16B; per-lane LDS ptr ignored - m104/m108), so the bank
// swizzle is applied on the GLOBAL side: lane filling linear slot seg fetches
// global segment cs=(seg&3)^((r>>1)&3); XOR involutive -> reader finds global
// (r,q) at lds_slot(r,q). R3/R5 measured SQ_LDS_BANK_CONFLICT == 0.
static __device__ __forceinline__ int lds_slot(int r, int cs) {
  return r * 4 + (cs ^ ((r >> 1) & 3));
}

static __device__ __forceinline__ void stage_tile(const unsigned short* __restrict__ src,
                                                  int row0, int k0,
                                                  unsigned short* lds, int tid) {
#pragma unroll
  for (int it = 0; it < 2; ++it) {
    int seg = it * 256 + tid;        // 512 linear 16B slots
    int r = seg >> 2;                // tile row
    int cs = (seg & 3) ^ ((r >> 1) & 3);   // swizzled global column segment
    gld_lds16(src + (size_t)(row0 + r) * 1024 + k0 + cs * 8, lds + seg * 8);
  }
}

// XCD-locality block swizzle for grid(8,96): XCD = linear_id % 8; each XCD
// owns 12 consecutive y-tiles (all x). R5 measured FETCH 117->54.6 MB.
static __device__ __forceinline__ void swizzle_xy(int& x, int& y) {
  int L = blockIdx.y * 8 + blockIdx.x;
  int xcd = L & 7;
  int s = L >> 3;                    // 0..95
  y = xcd * 12 + s % 12;
  x = s / 12;
}

// ---------------- permutation / routing ----------------
// Dense atomics from 64 waves (~3 us). R7 lesson: spreading these 16384
// atomicAdds across 8192 blocks (one per block, block waiting on it) made a
// 100 us latency-bound kernel. Keep routing dense and separate.
__global__ void perm_kernel(const int* __restrict__ idx, const float* __restrict__ tw,
                            int* __restrict__ cnt, int* __restrict__ rowdst,
                            int* __restrict__ inv, float* __restrict__ rowscale) {
  int i = blockIdx.x * 256 + threadIdx.x;        // i < TTOK*KTOP
  int e = idx[i];
  int pos = atomicAdd(&cnt[e], 1);               // order within expert irrelevant
  int j = e * CPER + pos;
  rowdst[j] = i >> 1;                            // token id (KTOP==2)
  rowscale[j] = tw[i];                           // topk weight -> gemm2 epilogue
  inv[i] = j;                                    // inverse permutation for combine
}

// ---------------- pack activations + shared gate ----------------
// grid 12288 blocks x 256 threads. Rows 0..8191: permuted MoE copies (via
// rowdst, no atomics). Rows 8192..12287: raw tokens; also compute the
// sigmoid-gate dot(hidden[t], gw) -> rowscale[row] while the row is live.
__global__ void pack_gate_kernel(const float* __restrict__ x, const int* __restrict__ rowdst,
                                 const float* __restrict__ gw,
                                 float* __restrict__ rowscale,
                                 unsigned short* __restrict__ xall) {
  int j = blockIdx.x;
  int tid = threadIdx.x;
  int t = (j < 8192) ? rowdst[j] : (j - 8192);
  float4 v = ((const float4*)(x + (size_t)t * 1024))[tid];
  ushort4 o;
  o.x = f2bf(v.x); o.y = f2bf(v.y); o.z = f2bf(v.z); o.w = f2bf(v.w);
  ((ushort4*)(xall + (size_t)j * 1024))[tid] = o;
  if (j >= 8192) {
    float4 g = ((const float4*)gw)[tid];
    float s = v.x * g.x + v.y * g.y + v.z * g.z + v.w * g.w;
#pragma unroll
    for (int off = 32; off; off >>= 1) s += __shfl_down(s, off);
    __shared__ float ws[4];
    if ((tid & 63) == 0) ws[tid >> 6] = s;
    __syncthreads();
    if (tid == 0) {
      float tot = ws[0] + ws[1] + ws[2] + ws[3];
      rowscale[j] = 1.f / (1.f + __expf(-tot));
    }
  }
}

// ---------------- transpose + cast all 27 1024x1024 weight mats ----------------
// 64x64 tiles, float4 reads, ushort4 writes, LDS stride 65 (odd -> <=2-way).
// Outputs packed [9][1024][1024] per matrix kind; index 8 = shared expert.
__global__ void transw_kernel(const float* __restrict__ wg, const float* __restrict__ wu,
                              const float* __restrict__ wd, const float* __restrict__ sg,
                              const float* __restrict__ su, const float* __restrict__ sd,
                              unsigned short* __restrict__ owg, unsigned short* __restrict__ owu,
                              unsigned short* __restrict__ owd) {
  int z = blockIdx.z;
  const float* src; unsigned short* dst;
  if (z < 8)       { src = wg + (size_t)z * 1048576;        dst = owg + (size_t)z * 1048576; }
  else if (z < 16) { src = wu + (size_t)(z - 8) * 1048576;  dst = owu + (size_t)(z - 8) * 1048576; }
  else if (z < 24) { src = wd + (size_t)(z - 16) * 1048576; dst = owd + (size_t)(z - 16) * 1048576; }
  else if (z == 24){ src = sg; dst = owg + (size_t)8 * 1048576; }
  else if (z == 25){ src = su; dst = owu + (size_t)8 * 1048576; }
  else             { src = sd; dst = owd + (size_t)8 * 1048576; }
  __shared__ float tile[64][65];
  int bx = blockIdx.x * 64;   // src col base
  int by = blockIdx.y * 64;   // src row base
  int c4 = threadIdx.x & 15;  // float4 chunk within row
  int r0 = threadIdx.x >> 4;  // 0..15
#pragma unroll
  for (int i = 0; i < 4; ++i) {
    int r = r0 + 16 * i;
    float4 v = *(const float4*)&src[(size_t)(by + r) * 1024 + bx + c4 * 4];
    tile[r][c4 * 4 + 0] = v.x; tile[r][c4 * 4 + 1] = v.y;
    tile[r][c4 * 4 + 2] = v.z; tile[r][c4 * 4 + 3] = v.w;
  }
  __syncthreads();
#pragma unroll
  for (int i = 0; i < 4; ++i) {
    int f = r0 + 16 * i;       // dst row = src col bx+f
    ushort4 o;
    o.x = f2bf(tile[c4 * 4 + 0][f]);
    o.y = f2bf(tile[c4 * 4 + 1][f]);
    o.z = f2bf(tile[c4 * 4 + 2][f]);
    o.w = f2bf(tile[c4 * 4 + 3][f]);
    *(ushort4*)&dst[(size_t)(bx + f) * 1024 + by + c4 * 4] = o;
  }
}

// Expert id for a 128-row M-block: y<64 -> MoE expert y/8; else shared (8).
static __device__ __forceinline__ int eid_of(int y) { return (y < 64) ? (y >> 3) : 8; }

// ---------------- GEMM1: H = silu(A @ Wg) * (A @ Wu), bf16 out ----------------
// R5-proven config: BK=32, 2 blocks/CU. Do NOT raise launch_bounds: 128 AGPR
// acc + ~104 arch VGPRs ~= 232 total regs/wave -> 2 waves/EU is the true HW
// limit; (256,3) spilled accumulators to scratch (R6: WRITE 24.6->469 MB).
__global__ __launch_bounds__(256, 2) void gemm1_kernel(
    const unsigned short* __restrict__ A, const unsigned short* __restrict__ Bg,
    const unsigned short* __restrict__ Bu, unsigned short* __restrict__ H) {
  __shared__ __align__(16) unsigned short As[128 * 32];
  __shared__ __align__(16) unsigned short Bgs[128 * 32];
  __shared__ __align__(16) unsigned short Bus[128 * 32];
  int tid = threadIdx.x;
  int bx, by;
  swizzle_xy(bx, by);
  int e = eid_of(by);
  int row0 = by * 128;
  int col0 = bx * 128;
  const unsigned short* Bge = Bg + (size_t)e * 1048576;
  const unsigned short* Bue = Bu + (size_t)e * 1048576;

  int wave = tid >> 6, lane = tid & 63;
  int wm = wave >> 1, wn = wave & 1;             // 2x2 wave grid, 64x64 per wave
  int lr = lane & 15, q = lane >> 4;

  f32x4 accg[4][4], accu[4][4];
#pragma unroll
  for (int i = 0; i < 4; ++i)
#pragma unroll
    for (int j = 0; j < 4; ++j) {
      accg[i][j] = (f32x4){0.f, 0.f, 0.f, 0.f};
      accu[i][j] = (f32x4){0.f, 0.f, 0.f, 0.f};
    }

  for (int kt = 0; kt < 1024; kt += 32) {
    stage_tile(A, row0, kt, As, tid);
    stage_tile(Bge, col0, kt, Bgs, tid);
    stage_tile(Bue, col0, kt, Bus, tid);
    __syncthreads();                             // drains vmcnt for global_load_lds
    frag8 a[4], b0[4], b1[4];
#pragma unroll
    for (int i = 0; i < 4; ++i) {
      int r = wm * 64 + i * 16 + lr;
      a[i] = *(const frag8*)&As[lds_slot(r, q) * 8];
    }
#pragma unroll
    for (int j = 0; j < 4; ++j) {
      int r = wn * 64 + j * 16 + lr;
      b0[j] = *(const frag8*)&Bgs[lds_slot(r, q) * 8];
      b1[j] = *(const frag8*)&Bus[lds_slot(r, q) * 8];
    }
#pragma unroll
    for (int i = 0; i < 4; ++i)
#pragma unroll
      for (int j = 0; j < 4; ++j) {
        accg[i][j] = __builtin_amdgcn_mfma_f32_16x16x32_bf16(a[i], b0[j], accg[i][j], 0, 0, 0);
        accu[i][j] = __builtin_amdgcn_mfma_f32_16x16x32_bf16(a[i], b1[j], accu[i][j], 0, 0, 0);
      }
    __syncthreads();
  }
#pragma unroll
  for (int i = 0; i < 4; ++i)
#pragma unroll
    for (int j = 0; j < 4; ++j)
#pragma unroll
      for (int r = 0; r < 4; ++r) {
        int m = row0 + wm * 64 + i * 16 + q * 4 + r;   // C/D: row=quad*4+reg
        int n = col0 + wn * 64 + j * 16 + lr;          //       col=lane&15
        float gv = accg[i][j][r];
        float hv = gv / (1.f + __expf(-gv)) * accu[i][j][r];
        H[(size_t)m * 1024 + n] = f2bf(hv);
      }
}

// ---------------- GEMM2: Y = rowscale * (A @ Wd), bf16 out ----------------
__global__ __launch_bounds__(256, 2) void gemm2_kernel(
    const unsigned short* __restrict__ A, const unsigned short* __restrict__ B,
    const float* __restrict__ rowscale, unsigned short* __restrict__ Y) {
  __shared__ __align__(16) unsigned short As[128 * 32];
  __shared__ __align__(16) unsigned short Bs[128 * 32];
  int tid = threadIdx.x;
  int bx, by;
  swizzle_xy(bx, by);
  int e = eid_of(by);
  int row0 = by * 128;
  int col0 = bx * 128;
  const unsigned short* Be = B + (size_t)e * 1048576;

  int wave = tid >> 6, lane = tid & 63;
  int wm = wave >> 1, wn = wave & 1;
  int lr = lane & 15, q = lane >> 4;

  f32x4 acc[4][4];
#pragma unroll
  for (int i = 0; i < 4; ++i)
#pragma unroll
    for (int j = 0; j < 4; ++j) acc[i][j] = (f32x4){0.f, 0.f, 0.f, 0.f};

  for (int kt = 0; kt < 1024; kt += 32) {
    stage_tile(A, row0, kt, As, tid);
    stage_tile(Be, col0, kt, Bs, tid);
    __syncthreads();
    frag8 a[4], b[4];
#pragma unroll
    for (int i = 0; i < 4; ++i) {
      int r = wm * 64 + i * 16 + lr;
      a[i] = *(const frag8*)&As[lds_slot(r, q) * 8];
    }
#pragma unroll
    for (int j = 0; j < 4; ++j) {
      int r = wn * 64 + j * 16 + lr;
      b[j] = *(const frag8*)&Bs[lds_slot(r, q) * 8];
    }
#pragma unroll
    for (int i = 0; i < 4; ++i)
#pragma unroll
      for (int j = 0; j < 4; ++j)
        acc[i][j] = __builtin_amdgcn_mfma_f32_16x16x32_bf16(a[i], b[j], acc[i][j], 0, 0, 0);
    __syncthreads();
  }
#pragma unroll
  for (int i = 0; i < 4; ++i)
#pragma unroll
    for (int r = 0; r < 4; ++r) {
      int m = row0 + wm * 64 + i * 16 + q * 4 + r;
      float sc = rowscale[m];
#pragma unroll
      for (int j = 0; j < 4; ++j) {
        int n = col0 + wn * 64 + j * 16 + lr;
        Y[(size_t)m * 1024 + n] = f2bf(sc * acc[i][j][r]);
      }
    }
}

// ---------------- final combine: out[t] = Y[j0] + Y[j1] + Y[8192+t] ----------
__global__ void combine_kernel(const unsigned short* __restrict__ Y,
                               const int* __restrict__ inv, float* __restrict__ out) {
  int t = blockIdx.x;
  int c = threadIdx.x;                           // 256 threads * 4 elems
  int j0 = inv[2 * t], j1 = inv[2 * t + 1];
  ushort4 a = ((const ushort4*)(Y + (size_t)j0 * 1024))[c];
  ushort4 b = ((const ushort4*)(Y + (size_t)j1 * 1024))[c];
  ushort4 s = ((const ushort4*)(Y + (size_t)(8192 + t) * 1024))[c];
  float4 o;
  o.x = bf2f(a.x) + bf2f(b.x) + bf2f(s.x);
  o.y = bf2f(a.y) + bf2f(b.y) + bf2f(s.y);
  o.z = bf2f(a.z) + bf2f(b.z) + bf2f(s.z);
  o.w = bf2f(a.w) + bf2f(b.w) + bf2f(s.w);
  ((float4*)(out + (size_t)t * 1024))[c] = o;
}

extern "C" void kernel_launch(void* const* d_in, const int* in_sizes, int n_in,
                              void* d_out, int out_size, void* d_ws, size_t ws_size,
                              hipStream_t stream) {
  (void)in_sizes; (void)n_in; (void)out_size; (void)ws_size;
  const float* hidden  = (const float*)d_in[0];
  const float* topk_w  = (const float*)d_in[1];
  const float* w_gate  = (const float*)d_in[2];
  const float* w_up    = (const float*)d_in[3];
  const float* w_down  = (const float*)d_in[4];
  const float* sw_gate = (const float*)d_in[5];
  const float* sw_up   = (const float*)d_in[6];
  const float* sw_down = (const float*)d_in[7];
  const float* sgw     = (const float*)d_in[8];
  const int*   topk_i  = (const int*)d_in[9];
  float* out = (float*)d_out;

  char* p = (char*)d_ws;
  auto alloc = [&](size_t bytes) {
    char* r = p;
    p += (bytes + 255) & ~(size_t)255;
    return r;
  };
  unsigned short* Wg_all = (unsigned short*)alloc((size_t)9 * 1048576 * 2);  // [9][1024][1024]
  unsigned short* Wu_all = (unsigned short*)alloc((size_t)9 * 1048576 * 2);
  unsigned short* Wd_all = (unsigned short*)alloc((size_t)9 * 1048576 * 2);
  unsigned short* Xall   = (unsigned short*)alloc((size_t)MROWS * 1024 * 2); // also reused as Y
  unsigned short* Hall   = (unsigned short*)alloc((size_t)MROWS * 1024 * 2);
  int*   cnt      = (int*)alloc(NE * 4);
  int*   rowdst   = (int*)alloc((size_t)TTOK * KTOP * 4);
  int*   inv      = (int*)alloc((size_t)TTOK * KTOP * 4);
  float* rowscale = (float*)alloc((size_t)MROWS * 4);
  unsigned short* Yall = Xall;   // Xall is dead after gemm1; alias to save ws

  hipMemsetAsync(cnt, 0, NE * 4, stream);

  perm_kernel<<<TTOK * KTOP / 256, 256, 0, stream>>>(topk_i, topk_w, cnt, rowdst, inv, rowscale);
  pack_gate_kernel<<<MROWS, 256, 0, stream>>>(hidden, rowdst, sgw, rowscale, Xall);
  transw_kernel<<<dim3(16, 16, 27), 256, 0, stream>>>(
      w_gate, w_up, w_down, sw_gate, sw_up, sw_down, Wg_all, Wu_all, Wd_all);

  gemm1_kernel<<<dim3(8, 96), 256, 0, stream>>>(Xall, Wg_all, Wu_all, Hall);
  gemm2_kernel<<<dim3(8, 96), 256, 0, stream>>>(Hall, Wd_all, rowscale, Yall);
  combine_kernel<<<TTOK, 256, 0, stream>>>(Yall, inv, out);
}

// Round 9
// 312.310 us; speedup vs baseline: 1.4006x; 1.0211x over previous
//
#include <hip/hip_runtime.h>
#include <hip/hip_bf16.h>
#include <cstdint>
#include <cstddef>

// Problem constants (fixed by the reference):
#define TTOK 4096
#define DM   1024
#define NE   8
#define KTOP 2
#define FFD  1024
#define CPER 1024       // TTOK*KTOP/NE tokens per expert (balanced)
#define MROWS 12288     // 8192 MoE permuted rows + 4096 shared rows

typedef __attribute__((ext_vector_type(8))) short frag8;   // 8 bf16 = 4 VGPRs
typedef __attribute__((ext_vector_type(4))) float f32x4;   // MFMA accumulator

static __device__ __forceinline__ unsigned short f2bf(float f) {
  unsigned int u = __float_as_uint(f);
  u += 0x7fff + ((u >> 16) & 1);     // round-to-nearest-even
  return (unsigned short)(u >> 16);
}
static __device__ __forceinline__ float bf2f(unsigned short u) {
  return __uint_as_float((unsigned int)u << 16);
}

static __device__ __forceinline__ void gld_lds16(const unsigned short* g, unsigned short* l) {
  __builtin_amdgcn_global_load_lds(
      (const __attribute__((address_space(1))) unsigned int*)g,
      (__attribute__((address_space(3))) unsigned int*)l,
      16, 0, 0);
}

// BK=32 tile: 128 rows x 4 segments of 16B. global_load_lds writes LINEAR LDS
// (wave base + lane*16B; per-lane LDS ptr ignored - m104/m108), so the bank
// swizzle is applied on the GLOBAL side: lane filling linear slot seg fetches
// global segment cs=(seg&3)^((r>>1)&3); XOR involutive -> reader finds global
// (r,q) at lds_slot(r,q). R3/R5/R8 measured SQ_LDS_BANK_CONFLICT == 0.
static __device__ __forceinline__ int lds_slot(int r, int cs) {
  return r * 4 + (cs ^ ((r >> 1) & 3));
}

static __device__ __forceinline__ void stage_tile(const unsigned short* __restrict__ src,
                                                  int row0, int k0,
                                                  unsigned short* lds, int tid) {
#pragma unroll
  for (int it = 0; it < 2; ++it) {
    int seg = it * 256 + tid;        // 512 linear 16B slots
    int r = seg >> 2;                // tile row
    int cs = (seg & 3) ^ ((r >> 1) & 3);   // swizzled global column segment
    gld_lds16(src + (size_t)(row0 + r) * 1024 + k0 + cs * 8, lds + seg * 8);
  }
}

// XCD-locality block swizzle for grid(8,96): XCD = linear_id % 8; each XCD
// owns 12 consecutive y-tiles (all x). R5 measured FETCH 117->54.6 MB.
static __device__ __forceinline__ void swizzle_xy(int& x, int& y) {
  int L = blockIdx.y * 8 + blockIdx.x;
  int xcd = L & 7;
  int s = L >> 3;                    // 0..95
  y = xcd * 12 + s % 12;
  x = s / 12;
}

// ---------------- permutation / routing ----------------
// Dense atomics from 64 waves (~3 us; R7: never spread these across blocks).
// rowsrc[j] = source token for permuted row j (identity for shared rows).
__global__ void perm_kernel(const int* __restrict__ idx, const float* __restrict__ tw,
                            int* __restrict__ cnt, int* __restrict__ rowsrc,
                            int* __restrict__ inv, float* __restrict__ rowscale) {
  int i = blockIdx.x * 256 + threadIdx.x;        // i < TTOK*KTOP
  int e = idx[i];
  int pos = atomicAdd(&cnt[e], 1);               // order within expert irrelevant
  int j = e * CPER + pos;
  rowsrc[j] = i >> 1;                            // token id (KTOP==2)
  rowscale[j] = tw[i];                           // topk weight -> gemm2 epilogue
  inv[i] = j;                                    // inverse permutation for combine
  if (i < TTOK) rowsrc[8192 + i] = i;            // shared rows: identity
}

// ---------------- convert hidden -> bf16 + shared gate ----------------
// One wave per row, 4 rows per block, 1024 blocks. Each lane: 4 independent
// float4 loads (deep MLP). R8 lesson: 12288 one-row blocks ran latency-bound
// at ~45 us; fat waves over the 4096-row buffer are ~7 us.
__global__ void conv_gate_kernel(const float* __restrict__ x, const float* __restrict__ gw,
                                 float* __restrict__ rowscale,
                                 unsigned short* __restrict__ xb) {
  int row = blockIdx.x * 4 + (threadIdx.x >> 6);
  int lane = threadIdx.x & 63;
  const float4* xr = (const float4*)(x + (size_t)row * 1024);
  const float4* wr = (const float4*)gw;
  ushort4* ob = (ushort4*)(xb + (size_t)row * 1024);
  float s = 0.f;
#pragma unroll
  for (int c = 0; c < 4; ++c) {
    int k = lane + 64 * c;
    float4 v = xr[k];
    float4 g = wr[k];
    s += v.x * g.x + v.y * g.y + v.z * g.z + v.w * g.w;
    ushort4 o;
    o.x = f2bf(v.x); o.y = f2bf(v.y); o.z = f2bf(v.z); o.w = f2bf(v.w);
    ob[k] = o;
  }
#pragma unroll
  for (int off = 32; off; off >>= 1) s += __shfl_down(s, off);
  if (lane == 0) rowscale[8192 + row] = 1.f / (1.f + __expf(-s));
}

// ---------------- transpose + cast all 27 1024x1024 weight mats ----------------
// 64x64 tiles, float4 reads, ushort4 writes, LDS stride 65 (odd -> <=2-way).
// Outputs packed [9][1024][1024] per matrix kind; index 8 = shared expert.
__global__ void transw_kernel(const float* __restrict__ wg, const float* __restrict__ wu,
                              const float* __restrict__ wd, const float* __restrict__ sg,
                              const float* __restrict__ su, const float* __restrict__ sd,
                              unsigned short* __restrict__ owg, unsigned short* __restrict__ owu,
                              unsigned short* __restrict__ owd) {
  int z = blockIdx.z;
  const float* src; unsigned short* dst;
  if (z < 8)       { src = wg + (size_t)z * 1048576;        dst = owg + (size_t)z * 1048576; }
  else if (z < 16) { src = wu + (size_t)(z - 8) * 1048576;  dst = owu + (size_t)(z - 8) * 1048576; }
  else if (z < 24) { src = wd + (size_t)(z - 16) * 1048576; dst = owd + (size_t)(z - 16) * 1048576; }
  else if (z == 24){ src = sg; dst = owg + (size_t)8 * 1048576; }
  else if (z == 25){ src = su; dst = owu + (size_t)8 * 1048576; }
  else             { src = sd; dst = owd + (size_t)8 * 1048576; }
  __shared__ float tile[64][65];
  int bx = blockIdx.x * 64;   // src col base
  int by = blockIdx.y * 64;   // src row base
  int c4 = threadIdx.x & 15;  // float4 chunk within row
  int r0 = threadIdx.x >> 4;  // 0..15
#pragma unroll
  for (int i = 0; i < 4; ++i) {
    int r = r0 + 16 * i;
    float4 v = *(const float4*)&src[(size_t)(by + r) * 1024 + bx + c4 * 4];
    tile[r][c4 * 4 + 0] = v.x; tile[r][c4 * 4 + 1] = v.y;
    tile[r][c4 * 4 + 2] = v.z; tile[r][c4 * 4 + 3] = v.w;
  }
  __syncthreads();
#pragma unroll
  for (int i = 0; i < 4; ++i) {
    int f = r0 + 16 * i;       // dst row = src col bx+f
    ushort4 o;
    o.x = f2bf(tile[c4 * 4 + 0][f]);
    o.y = f2bf(tile[c4 * 4 + 1][f]);
    o.z = f2bf(tile[c4 * 4 + 2][f]);
    o.w = f2bf(tile[c4 * 4 + 3][f]);
    *(ushort4*)&dst[(size_t)(bx + f) * 1024 + by + c4 * 4] = o;
  }
}

// Expert id for a 128-row M-block: y<64 -> MoE expert y/8; else shared (8).
static __device__ __forceinline__ int eid_of(int y) { return (y < 64) ? (y >> 3) : 8; }

// ---------------- GEMM1: H = silu(A @ Wg) * (A @ Wu), bf16 out ----------------
// A is gathered on the fly: tile row r reads token rowsrc[row0+r] from the
// 8.4 MB bf16 Xbf (stays hot in L2) -> no materialized 12288-row activation
// copy. Config: BK=32, 2 blocks/CU (R6: (256,3) spills the 128 acc regs).
__global__ __launch_bounds__(256, 2) void gemm1_kernel(
    const unsigned short* __restrict__ A, const int* __restrict__ rowsrc,
    const unsigned short* __restrict__ Bg, const unsigned short* __restrict__ Bu,
    unsigned short* __restrict__ H) {
  __shared__ __align__(16) unsigned short As[128 * 32];
  __shared__ __align__(16) unsigned short Bgs[128 * 32];
  __shared__ __align__(16) unsigned short Bus[128 * 32];
  int tid = threadIdx.x;
  int bx, by;
  swizzle_xy(bx, by);
  int e = eid_of(by);
  int row0 = by * 128;
  int col0 = bx * 128;
  const unsigned short* Bge = Bg + (size_t)e * 1048576;
  const unsigned short* Bue = Bu + (size_t)e * 1048576;

  // per-thread A staging sources (fixed across K): 2 segments, swizzled col
  int sA0 = tid, sA1 = 256 + tid;
  int rA0 = sA0 >> 2, rA1 = sA1 >> 2;
  int cA0 = (sA0 & 3) ^ ((rA0 >> 1) & 3);
  int cA1 = (sA1 & 3) ^ ((rA1 >> 1) & 3);
  const unsigned short* pA0 = A + (size_t)rowsrc[row0 + rA0] * 1024 + cA0 * 8;
  const unsigned short* pA1 = A + (size_t)rowsrc[row0 + rA1] * 1024 + cA1 * 8;

  int wave = tid >> 6, lane = tid & 63;
  int wm = wave >> 1, wn = wave & 1;             // 2x2 wave grid, 64x64 per wave
  int lr = lane & 15, q = lane >> 4;

  f32x4 accg[4][4], accu[4][4];
#pragma unroll
  for (int i = 0; i < 4; ++i)
#pragma unroll
    for (int j = 0; j < 4; ++j) {
      accg[i][j] = (f32x4){0.f, 0.f, 0.f, 0.f};
      accu[i][j] = (f32x4){0.f, 0.f, 0.f, 0.f};
    }

  for (int kt = 0; kt < 1024; kt += 32) {
    gld_lds16(pA0 + kt, As + sA0 * 8);
    gld_lds16(pA1 + kt, As + sA1 * 8);
    stage_tile(Bge, col0, kt, Bgs, tid);
    stage_tile(Bue, col0, kt, Bus, tid);
    __syncthreads();                             // drains vmcnt for global_load_lds
    frag8 a[4], b0[4], b1[4];
#pragma unroll
    for (int i = 0; i < 4; ++i) {
      int r = wm * 64 + i * 16 + lr;
      a[i] = *(const frag8*)&As[lds_slot(r, q) * 8];
    }
#pragma unroll
    for (int j = 0; j < 4; ++j) {
      int r = wn * 64 + j * 16 + lr;
      b0[j] = *(const frag8*)&Bgs[lds_slot(r, q) * 8];
      b1[j] = *(const frag8*)&Bus[lds_slot(r, q) * 8];
    }
#pragma unroll
    for (int i = 0; i < 4; ++i)
#pragma unroll
      for (int j = 0; j < 4; ++j) {
        accg[i][j] = __builtin_amdgcn_mfma_f32_16x16x32_bf16(a[i], b0[j], accg[i][j], 0, 0, 0);
        accu[i][j] = __builtin_amdgcn_mfma_f32_16x16x32_bf16(a[i], b1[j], accu[i][j], 0, 0, 0);
      }
    __syncthreads();
  }
#pragma unroll
  for (int i = 0; i < 4; ++i)
#pragma unroll
    for (int j = 0; j < 4; ++j)
#pragma unroll
      for (int r = 0; r < 4; ++r) {
        int m = row0 + wm * 64 + i * 16 + q * 4 + r;   // C/D: row=quad*4+reg
        int n = col0 + wn * 64 + j * 16 + lr;          //       col=lane&15
        float gv = accg[i][j][r];
        float hv = gv / (1.f + __expf(-gv)) * accu[i][j][r];
        H[(size_t)m * 1024 + n] = f2bf(hv);
      }
}

// ---------------- GEMM2: Y = rowscale * (A @ Wd), bf16 out ----------------
__global__ __launch_bounds__(256, 2) void gemm2_kernel(
    const unsigned short* __restrict__ A, const unsigned short* __restrict__ B,
    const float* __restrict__ rowscale, unsigned short* __restrict__ Y) {
  __shared__ __align__(16) unsigned short As[128 * 32];
  __shared__ __align__(16) unsigned short Bs[128 * 32];
  int tid = threadIdx.x;
  int bx, by;
  swizzle_xy(bx, by);
  int e = eid_of(by);
  int row0 = by * 128;
  int col0 = bx * 128;
  const unsigned short* Be = B + (size_t)e * 1048576;

  int wave = tid >> 6, lane = tid & 63;
  int wm = wave >> 1, wn = wave & 1;
  int lr = lane & 15, q = lane >> 4;

  f32x4 acc[4][4];
#pragma unroll
  for (int i = 0; i < 4; ++i)
#pragma unroll
    for (int j = 0; j < 4; ++j) acc[i][j] = (f32x4){0.f, 0.f, 0.f, 0.f};

  for (int kt = 0; kt < 1024; kt += 32) {
    stage_tile(A, row0, kt, As, tid);
    stage_tile(Be, col0, kt, Bs, tid);
    __syncthreads();
    frag8 a[4], b[4];
#pragma unroll
    for (int i = 0; i < 4; ++i) {
      int r = wm * 64 + i * 16 + lr;
      a[i] = *(const frag8*)&As[lds_slot(r, q) * 8];
    }
#pragma unroll
    for (int j = 0; j < 4; ++j) {
      int r = wn * 64 + j * 16 + lr;
      b[j] = *(const frag8*)&Bs[lds_slot(r, q) * 8];
    }
#pragma unroll
    for (int i = 0; i < 4; ++i)
#pragma unroll
      for (int j = 0; j < 4; ++j)
        acc[i][j] = __builtin_amdgcn_mfma_f32_16x16x32_bf16(a[i], b[j], acc[i][j], 0, 0, 0);
    __syncthreads();
  }
#pragma unroll
  for (int i = 0; i < 4; ++i)
#pragma unroll
    for (int r = 0; r < 4; ++r) {
      int m = row0 + wm * 64 + i * 16 + q * 4 + r;
      float sc = rowscale[m];
#pragma unroll
      for (int j = 0; j < 4; ++j) {
        int n = col0 + wn * 64 + j * 16 + lr;
        Y[(size_t)m * 1024 + n] = f2bf(sc * acc[i][j][r]);
      }
    }
}

// ---------------- final combine: out[t] = Y[j0] + Y[j1] + Y[8192+t] ----------
// Flat slot mapping (slot = t*256 + float4-chunk), 2 independent slots per
// thread -> MLP; avoids the one-row-per-block latency-bound shape (R8 lesson).
__global__ void combine_kernel(const unsigned short* __restrict__ Y,
                               const int* __restrict__ inv, float* __restrict__ out) {
  int base = blockIdx.x * 256 + threadIdx.x;
#pragma unroll
  for (int k = 0; k < 2; ++k) {
    int slot = base + k * 524288;                // 2048 blocks * 256 threads
    int t = slot >> 8;
    int c = slot & 255;
    int j0 = inv[2 * t], j1 = inv[2 * t + 1];
    ushort4 a = ((const ushort4*)(Y + (size_t)j0 * 1024))[c];
    ushort4 b = ((const ushort4*)(Y + (size_t)j1 * 1024))[c];
    ushort4 s = ((const ushort4*)(Y + (size_t)(8192 + t) * 1024))[c];
    float4 o;
    o.x = bf2f(a.x) + bf2f(b.x) + bf2f(s.x);
    o.y = bf2f(a.y) + bf2f(b.y) + bf2f(s.y);
    o.z = bf2f(a.z) + bf2f(b.z) + bf2f(s.z);
    o.w = bf2f(a.w) + bf2f(b.w) + bf2f(s.w);
    ((float4*)(out + (size_t)t * 1024))[c] = o;
  }
}

extern "C" void kernel_launch(void* const* d_in, const int* in_sizes, int n_in,
                              void* d_out, int out_size, void* d_ws, size_t ws_size,
                              hipStream_t stream) {
  (void)in_sizes; (void)n_in; (void)out_size; (void)ws_size;
  const float* hidden  = (const float*)d_in[0];
  const float* topk_w  = (const float*)d_in[1];
  const float* w_gate  = (const float*)d_in[2];
  const float* w_up    = (const float*)d_in[3];
  const float* w_down  = (const float*)d_in[4];
  const float* sw_gate = (const float*)d_in[5];
  const float* sw_up   = (const float*)d_in[6];
  const float* sw_down = (const float*)d_in[7];
  const float* sgw     = (const float*)d_in[8];
  const int*   topk_i  = (const int*)d_in[9];
  float* out = (float*)d_out;

  char* p = (char*)d_ws;
  auto alloc = [&](size_t bytes) {
    char* r = p;
    p += (bytes + 255) & ~(size_t)255;
    return r;
  };
  unsigned short* Wg_all = (unsigned short*)alloc((size_t)9 * 1048576 * 2);  // [9][1024][1024]
  unsigned short* Wu_all = (unsigned short*)alloc((size_t)9 * 1048576 * 2);
  unsigned short* Wd_all = (unsigned short*)alloc((size_t)9 * 1048576 * 2);
  unsigned short* Xbf    = (unsigned short*)alloc((size_t)TTOK * 1024 * 2);  // bf16 hidden
  unsigned short* Hall   = (unsigned short*)alloc((size_t)MROWS * 1024 * 2);
  unsigned short* Yall   = (unsigned short*)alloc((size_t)MROWS * 1024 * 2);
  int*   cnt      = (int*)alloc(NE * 4);
  int*   rowsrc   = (int*)alloc((size_t)MROWS * 4);
  int*   inv      = (int*)alloc((size_t)TTOK * KTOP * 4);
  float* rowscale = (float*)alloc((size_t)MROWS * 4);

  hipMemsetAsync(cnt, 0, NE * 4, stream);

  perm_kernel<<<TTOK * KTOP / 256, 256, 0, stream>>>(topk_i, topk_w, cnt, rowsrc, inv, rowscale);
  conv_gate_kernel<<<TTOK / 4, 256, 0, stream>>>(hidden, sgw, rowscale, Xbf);
  transw_kernel<<<dim3(16, 16, 27), 256, 0, stream>>>(
      w_gate, w_up, w_down, sw_gate, sw_up, sw_down, Wg_all, Wu_all, Wd_all);

  gemm1_kernel<<<dim3(8, 96), 256, 0, stream>>>(Xbf, rowsrc, Wg_all, Wu_all, Hall);
  gemm2_kernel<<<dim3(8, 96), 256, 0, stream>>>(Hall, Wd_all, rowscale, Yall);
  combine_kernel<<<2048, 256, 0, stream>>>(Yall, inv, out);
}

// Round 10
// 296.984 us; speedup vs baseline: 1.4729x; 1.0516x over previous
//
#include <hip/hip_runtime.h>
#include <hip/hip_bf16.h>
#include <cstdint>
#include <cstddef>

// Problem constants (fixed by the reference):
#define TTOK 4096
#define DM   1024
#define NE   8
#define KTOP 2
#define FFD  1024
#define CPER 1024       // TTOK*KTOP/NE tokens per expert (balanced)
#define MROWS 12288     // 8192 MoE permuted rows + 4096 shared rows

typedef __attribute__((ext_vector_type(8))) short frag8;   // 8 bf16 = 4 VGPRs
typedef __attribute__((ext_vector_type(4))) float f32x4;   // MFMA accumulator

static __device__ __forceinline__ unsigned short f2bf(float f) {
  unsigned int u = __float_as_uint(f);
  u += 0x7fff + ((u >> 16) & 1);     // round-to-nearest-even
  return (unsigned short)(u >> 16);
}
static __device__ __forceinline__ float bf2f(unsigned short u) {
  return __uint_as_float((unsigned int)u << 16);
}

static __device__ __forceinline__ void gld_lds16(const unsigned short* g, unsigned short* l) {
  __builtin_amdgcn_global_load_lds(
      (const __attribute__((address_space(1))) unsigned int*)g,
      (__attribute__((address_space(3))) unsigned int*)l,
      16, 0, 0);
}

// BK=64 tile: 128 rows x 8 segments of 16B. global_load_lds writes LINEAR LDS
// (wave base + lane*16B; per-lane LDS ptr ignored - m104/m108) -> bank swizzle
// on the GLOBAL side: lane filling linear slot seg fetches global segment
// cs=(seg&7)^(r&7); XOR involutive -> reader finds global (r,c) at
// lds_slot64(r,c). R4 measured SQ_LDS_BANK_CONFLICT == 0 with this pattern.
// NOTE: BK=64 is safe ONLY with the XCD swizzle (R4's 260 MB FETCH blowup was
// the missing swizzle, not BK) and ONLY at (256,2) (R6: (256,3) spills acc).
static __device__ __forceinline__ int lds_slot64(int r, int c) {
  return r * 8 + (c ^ (r & 7));
}

static __device__ __forceinline__ void stage_tile64(const unsigned short* __restrict__ src,
                                                    int row0, int k0,
                                                    unsigned short* lds, int tid) {
#pragma unroll
  for (int it = 0; it < 4; ++it) {
    int seg = it * 256 + tid;              // 1024 linear 16B slots
    int r = seg >> 3;                      // tile row
    int cs = (seg & 7) ^ (r & 7);          // swizzled global column segment
    gld_lds16(src + (size_t)(row0 + r) * 1024 + k0 + cs * 8, lds + seg * 8);
  }
}

// XCD-locality block swizzle for grid(8,96): XCD = linear_id % 8; each XCD
// owns 12 consecutive y-tiles (all x). R5 measured FETCH 117->54.6 MB.
static __device__ __forceinline__ void swizzle_xy(int& x, int& y) {
  int L = blockIdx.y * 8 + blockIdx.x;
  int xcd = L & 7;
  int s = L >> 3;                    // 0..95
  y = xcd * 12 + s % 12;
  x = s / 12;
}

// ---------------- fused routing + convert + shared gate ----------------
// 1024 blocks x 256 threads; one wave per row (4 rows/block) converts hidden
// -> bf16 and computes the sigmoid gate. Blocks 0..31 additionally run the
// routing (dense atomics from 8192 threads, ~3 us; R7: never spread these
// one-per-block).
__global__ void prep_kernel(const float* __restrict__ x, const float* __restrict__ gw,
                            const int* __restrict__ idx, const float* __restrict__ tw,
                            int* __restrict__ cnt, int* __restrict__ rowsrc,
                            int* __restrict__ inv, float* __restrict__ rowscale,
                            unsigned short* __restrict__ xb) {
  if (blockIdx.x < 32) {
    int i = blockIdx.x * 256 + threadIdx.x;      // i < TTOK*KTOP
    int e = idx[i];
    int pos = atomicAdd(&cnt[e], 1);             // order within expert irrelevant
    int j = e * CPER + pos;
    rowsrc[j] = i >> 1;                          // token id (KTOP==2)
    rowscale[j] = tw[i];                         // topk weight -> gemm2 epilogue
    inv[i] = j;                                  // inverse perm for combine
    if (i < TTOK) rowsrc[8192 + i] = i;          // shared rows: identity
  }
  int row = blockIdx.x * 4 + (threadIdx.x >> 6);
  int lane = threadIdx.x & 63;
  const float4* xr = (const float4*)(x + (size_t)row * 1024);
  const float4* wr = (const float4*)gw;
  ushort4* ob = (ushort4*)(xb + (size_t)row * 1024);
  float s = 0.f;
#pragma unroll
  for (int c = 0; c < 4; ++c) {
    int k = lane + 64 * c;
    float4 v = xr[k];
    float4 g = wr[k];
    s += v.x * g.x + v.y * g.y + v.z * g.z + v.w * g.w;
    ushort4 o;
    o.x = f2bf(v.x); o.y = f2bf(v.y); o.z = f2bf(v.z); o.w = f2bf(v.w);
    ob[k] = o;
  }
#pragma unroll
  for (int off = 32; off; off >>= 1) s += __shfl_down(s, off);
  if (lane == 0) rowscale[8192 + row] = 1.f / (1.f + __expf(-s));
}

// ---------------- transpose + cast all 27 1024x1024 weight mats ----------------
// 64x64 tiles, float4 reads, ushort4 writes, LDS stride 65 (odd -> <=2-way).
// Outputs packed [9][1024][1024] per matrix kind; index 8 = shared expert.
__global__ void transw_kernel(const float* __restrict__ wg, const float* __restrict__ wu,
                              const float* __restrict__ wd, const float* __restrict__ sg,
                              const float* __restrict__ su, const float* __restrict__ sd,
                              unsigned short* __restrict__ owg, unsigned short* __restrict__ owu,
                              unsigned short* __restrict__ owd) {
  int z = blockIdx.z;
  const float* src; unsigned short* dst;
  if (z < 8)       { src = wg + (size_t)z * 1048576;        dst = owg + (size_t)z * 1048576; }
  else if (z < 16) { src = wu + (size_t)(z - 8) * 1048576;  dst = owu + (size_t)(z - 8) * 1048576; }
  else if (z < 24) { src = wd + (size_t)(z - 16) * 1048576; dst = owd + (size_t)(z - 16) * 1048576; }
  else if (z == 24){ src = sg; dst = owg + (size_t)8 * 1048576; }
  else if (z == 25){ src = su; dst = owu + (size_t)8 * 1048576; }
  else             { src = sd; dst = owd + (size_t)8 * 1048576; }
  __shared__ float tile[64][65];
  int bx = blockIdx.x * 64;   // src col base
  int by = blockIdx.y * 64;   // src row base
  int c4 = threadIdx.x & 15;  // float4 chunk within row
  int r0 = threadIdx.x >> 4;  // 0..15
#pragma unroll
  for (int i = 0; i < 4; ++i) {
    int r = r0 + 16 * i;
    float4 v = *(const float4*)&src[(size_t)(by + r) * 1024 + bx + c4 * 4];
    tile[r][c4 * 4 + 0] = v.x; tile[r][c4 * 4 + 1] = v.y;
    tile[r][c4 * 4 + 2] = v.z; tile[r][c4 * 4 + 3] = v.w;
  }
  __syncthreads();
#pragma unroll
  for (int i = 0; i < 4; ++i) {
    int f = r0 + 16 * i;       // dst row = src col bx+f
    ushort4 o;
    o.x = f2bf(tile[c4 * 4 + 0][f]);
    o.y = f2bf(tile[c4 * 4 + 1][f]);
    o.z = f2bf(tile[c4 * 4 + 2][f]);
    o.w = f2bf(tile[c4 * 4 + 3][f]);
    *(ushort4*)&dst[(size_t)(bx + f) * 1024 + by + c4 * 4] = o;
  }
}

// Expert id for a 128-row M-block: y<64 -> MoE expert y/8; else shared (8).
static __device__ __forceinline__ int eid_of(int y) { return (y < 64) ? (y >> 3) : 8; }

// ---------------- GEMM1: H = silu(A @ Wg) * (A @ Wu), bf16 out ----------------
// A gathered on the fly from the 8.4 MB bf16 Xbf via rowsrc (R9: free).
// BK=64 halves barrier-drain count; LDS 48KB/block -> 2 blocks/CU.
__global__ __launch_bounds__(256, 2) void gemm1_kernel(
    const unsigned short* __restrict__ A, const int* __restrict__ rowsrc,
    const unsigned short* __restrict__ Bg, const unsigned short* __restrict__ Bu,
    unsigned short* __restrict__ H) {
  __shared__ __align__(16) unsigned short As[128 * 64];
  __shared__ __align__(16) unsigned short Bgs[128 * 64];
  __shared__ __align__(16) unsigned short Bus[128 * 64];
  int tid = threadIdx.x;
  int bx, by;
  swizzle_xy(bx, by);
  int e = eid_of(by);
  int row0 = by * 128;
  int col0 = bx * 128;
  const unsigned short* Bge = Bg + (size_t)e * 1048576;
  const unsigned short* Bue = Bu + (size_t)e * 1048576;

  // per-thread A staging sources (fixed across K): 4 segs, global-side swizzle
  const unsigned short* pA[4];
#pragma unroll
  for (int it = 0; it < 4; ++it) {
    int seg = it * 256 + tid;
    int r = seg >> 3;
    int cs = (seg & 7) ^ (r & 7);
    pA[it] = A + (size_t)rowsrc[row0 + r] * 1024 + cs * 8;
  }

  int wave = tid >> 6, lane = tid & 63;
  int wm = wave >> 1, wn = wave & 1;             // 2x2 wave grid, 64x64 per wave
  int lr = lane & 15, q = lane >> 4;

  f32x4 accg[4][4], accu[4][4];
#pragma unroll
  for (int i = 0; i < 4; ++i)
#pragma unroll
    for (int j = 0; j < 4; ++j) {
      accg[i][j] = (f32x4){0.f, 0.f, 0.f, 0.f};
      accu[i][j] = (f32x4){0.f, 0.f, 0.f, 0.f};
    }

  for (int kt = 0; kt < 1024; kt += 64) {
#pragma unroll
    for (int it = 0; it < 4; ++it)
      gld_lds16(pA[it] + kt, As + (it * 256 + tid) * 8);
    stage_tile64(Bge, col0, kt, Bgs, tid);
    stage_tile64(Bue, col0, kt, Bus, tid);
    __syncthreads();                             // drains vmcnt for global_load_lds
#pragma unroll
    for (int kk = 0; kk < 2; ++kk) {
      int c = kk * 4 + q;
      frag8 a[4], b0[4], b1[4];
#pragma unroll
      for (int i = 0; i < 4; ++i) {
        int r = wm * 64 + i * 16 + lr;
        a[i] = *(const frag8*)&As[lds_slot64(r, c) * 8];
      }
#pragma unroll
      for (int j = 0; j < 4; ++j) {
        int r = wn * 64 + j * 16 + lr;
        b0[j] = *(const frag8*)&Bgs[lds_slot64(r, c) * 8];
        b1[j] = *(const frag8*)&Bus[lds_slot64(r, c) * 8];
      }
#pragma unroll
      for (int i = 0; i < 4; ++i)
#pragma unroll
        for (int j = 0; j < 4; ++j) {
          accg[i][j] = __builtin_amdgcn_mfma_f32_16x16x32_bf16(a[i], b0[j], accg[i][j], 0, 0, 0);
          accu[i][j] = __builtin_amdgcn_mfma_f32_16x16x32_bf16(a[i], b1[j], accu[i][j], 0, 0, 0);
        }
    }
    __syncthreads();
  }
#pragma unroll
  for (int i = 0; i < 4; ++i)
#pragma unroll
    for (int j = 0; j < 4; ++j)
#pragma unroll
      for (int r = 0; r < 4; ++r) {
        int m = row0 + wm * 64 + i * 16 + q * 4 + r;   // C/D: row=quad*4+reg
        int n = col0 + wn * 64 + j * 16 + lr;          //       col=lane&15
        float gv = accg[i][j][r];
        float hv = gv / (1.f + __expf(-gv)) * accu[i][j][r];
        H[(size_t)m * 1024 + n] = f2bf(hv);
      }
}

// ---------------- GEMM2: Y = rowscale * (A @ Wd), bf16 out ----------------
// BK=64, LDS 32KB/block, 2 blocks/CU.
__global__ __launch_bounds__(256, 2) void gemm2_kernel(
    const unsigned short* __restrict__ A, const unsigned short* __restrict__ B,
    const float* __restrict__ rowscale, unsigned short* __restrict__ Y) {
  __shared__ __align__(16) unsigned short As[128 * 64];
  __shared__ __align__(16) unsigned short Bs[128 * 64];
  int tid = threadIdx.x;
  int bx, by;
  swizzle_xy(bx, by);
  int e = eid_of(by);
  int row0 = by * 128;
  int col0 = bx * 128;
  const unsigned short* Be = B + (size_t)e * 1048576;

  int wave = tid >> 6, lane = tid & 63;
  int wm = wave >> 1, wn = wave & 1;
  int lr = lane & 15, q = lane >> 4;

  f32x4 acc[4][4];
#pragma unroll
  for (int i = 0; i < 4; ++i)
#pragma unroll
    for (int j = 0; j < 4; ++j) acc[i][j] = (f32x4){0.f, 0.f, 0.f, 0.f};

  for (int kt = 0; kt < 1024; kt += 64) {
    stage_tile64(A, row0, kt, As, tid);
    stage_tile64(Be, col0, kt, Bs, tid);
    __syncthreads();
#pragma unroll
    for (int kk = 0; kk < 2; ++kk) {
      int c = kk * 4 + q;
      frag8 a[4], b[4];
#pragma unroll
      for (int i = 0; i < 4; ++i) {
        int r = wm * 64 + i * 16 + lr;
        a[i] = *(const frag8*)&As[lds_slot64(r, c) * 8];
      }
#pragma unroll
      for (int j = 0; j < 4; ++j) {
        int r = wn * 64 + j * 16 + lr;
        b[j] = *(const frag8*)&Bs[lds_slot64(r, c) * 8];
      }
#pragma unroll
      for (int i = 0; i < 4; ++i)
#pragma unroll
        for (int j = 0; j < 4; ++j)
          acc[i][j] = __builtin_amdgcn_mfma_f32_16x16x32_bf16(a[i], b[j], acc[i][j], 0, 0, 0);
    }
    __syncthreads();
  }
#pragma unroll
  for (int i = 0; i < 4; ++i)
#pragma unroll
    for (int r = 0; r < 4; ++r) {
      int m = row0 + wm * 64 + i * 16 + q * 4 + r;
      float sc = rowscale[m];
#pragma unroll
      for (int j = 0; j < 4; ++j) {
        int n = col0 + wn * 64 + j * 16 + lr;
        Y[(size_t)m * 1024 + n] = f2bf(sc * acc[i][j][r]);
      }
    }
}

// ---------------- final combine: out[t] = Y[j0] + Y[j1] + Y[8192+t] ----------
// Flat slot mapping, 2 independent slots/thread (R8 lesson: avoid one-row
// blocks).
__global__ void combine_kernel(const unsigned short* __restrict__ Y,
                               const int* __restrict__ inv, float* __restrict__ out) {
  int base = blockIdx.x * 256 + threadIdx.x;
#pragma unroll
  for (int k = 0; k < 2; ++k) {
    int slot = base + k * 524288;                // 2048 blocks * 256 threads
    int t = slot >> 8;
    int c = slot & 255;
    int j0 = inv[2 * t], j1 = inv[2 * t + 1];
    ushort4 a = ((const ushort4*)(Y + (size_t)j0 * 1024))[c];
    ushort4 b = ((const ushort4*)(Y + (size_t)j1 * 1024))[c];
    ushort4 s = ((const ushort4*)(Y + (size_t)(8192 + t) * 1024))[c];
    float4 o;
    o.x = bf2f(a.x) + bf2f(b.x) + bf2f(s.x);
    o.y = bf2f(a.y) + bf2f(b.y) + bf2f(s.y);
    o.z = bf2f(a.z) + bf2f(b.z) + bf2f(s.z);
    o.w = bf2f(a.w) + bf2f(b.w) + bf2f(s.w);
    ((float4*)(out + (size_t)t * 1024))[c] = o;
  }
}

extern "C" void kernel_launch(void* const* d_in, const int* in_sizes, int n_in,
                              void* d_out, int out_size, void* d_ws, size_t ws_size,
                              hipStream_t stream) {
  (void)in_sizes; (void)n_in; (void)out_size; (void)ws_size;
  const float* hidden  = (const float*)d_in[0];
  const float* topk_w  = (const float*)d_in[1];
  const float* w_gate  = (const float*)d_in[2];
  const float* w_up    = (const float*)d_in[3];
  const float* w_down  = (const float*)d_in[4];
  const float* sw_gate = (const float*)d_in[5];
  const float* sw_up   = (const float*)d_in[6];
  const float* sw_down = (const float*)d_in[7];
  const float* sgw     = (const float*)d_in[8];
  const int*   topk_i  = (const int*)d_in[9];
  float* out = (float*)d_out;

  char* p = (char*)d_ws;
  auto alloc = [&](size_t bytes) {
    char* r = p;
    p += (bytes + 255) & ~(size_t)255;
    return r;
  };
  unsigned short* Wg_all = (unsigned short*)alloc((size_t)9 * 1048576 * 2);  // [9][1024][1024]
  unsigned short* Wu_all = (unsigned short*)alloc((size_t)9 * 1048576 * 2);
  unsigned short* Wd_all = (unsigned short*)alloc((size_t)9 * 1048576 * 2);
  unsigned short* Xbf    = (unsigned short*)alloc((size_t)TTOK * 1024 * 2);  // bf16 hidden
  unsigned short* Hall   = (unsigned short*)alloc((size_t)MROWS * 1024 * 2);
  unsigned short* Yall   = (unsigned short*)alloc((size_t)MROWS * 1024 * 2);
  int*   cnt      = (int*)alloc(NE * 4);
  int*   rowsrc   = (int*)alloc((size_t)MROWS * 4);
  int*   inv      = (int*)alloc((size_t)TTOK * KTOP * 4);
  float* rowscale = (float*)alloc((size_t)MROWS * 4);

  hipMemsetAsync(cnt, 0, NE * 4, stream);

  prep_kernel<<<TTOK / 4, 256, 0, stream>>>(hidden, sgw, topk_i, topk_w,
                                            cnt, rowsrc, inv, rowscale, Xbf);
  transw_kernel<<<dim3(16, 16, 27), 256, 0, stream>>>(
      w_gate, w_up, w_down, sw_gate, sw_up, sw_down, Wg_all, Wu_all, Wd_all);

  gemm1_kernel<<<dim3(8, 96), 256, 0, stream>>>(Xbf, rowsrc, Wg_all, Wu_all, Hall);
  gemm2_kernel<<<dim3(8, 96), 256, 0, stream>>>(Hall, Wd_all, rowscale, Yall);
  combine_kernel<<<2048, 256, 0, stream>>>(Yall, inv, out);
}